// Round 9
// baseline (67.517 us; speedup 1.0000x reference)
//
#include <hip/hip_runtime.h>

typedef float v2f __attribute__((ext_vector_type(2)));

// Structural constants (mirror reference)
#define NPOSE 64
#define NROT  128
#define NATOM 8
#define EPS   1e-2f

#define TS    16                 // rotamer tile size
#define NTILE (NROT / TS)        // 8 tiles per axis
#define NPAIR (NTILE * (NTILE + 1) / 2)   // 36 tile pairs (ti <= tj)
#define CSTR  28                 // coord LDS row stride: 24 + 4 pad -> 112B, 16B-aligned rows
#define SSTR  17                 // result tile row stride (16 + 1 pad)

// R5 structure + streamed xj; natural pressure ~58 VGPR -> 8 waves/SIMD.
__global__ __launch_bounds__(256, 8) void rot_score_kernel(
    const float* __restrict__ coords,
    float* __restrict__ out)
{
    __shared__ float ldsI[TS * CSTR];
    __shared__ float ldsJ[TS * CSTR];
    __shared__ float res0[TS * SSTR];
    __shared__ float res1[TS * SSTR];

    const int bid = blockIdx.x;
    const int p   = bid / NPAIR;
    int t = bid - p * NPAIR;
    int ti = 0;
    while (t >= NTILE - ti) { t -= NTILE - ti; ++ti; }   // unrank upper triangle
    const int tj = ti + t;

    const int tid = threadIdx.x;
    const float* src = coords + (size_t)p * (NROT * NATOM * 3);

    // Stage the two 16-rotamer coordinate sets (16 x 24 floats each), coalesced reads.
    for (int idx = tid; idx < 2 * TS * 24; idx += 256) {
        const int set = idx >= TS * 24;
        const int loc = idx - set * (TS * 24);
        const int r   = loc / 24;
        const int k   = loc - r * 24;
        const float v = src[(set ? tj : ti) * (TS * 24) + loc];
        (set ? ldsJ : ldsI)[r * CSTR + k] = v;
    }
    __syncthreads();

    const int ty = tid >> 4;    // i within tile (0..15)
    const int tx = tid & 15;    // j within tile (0..15)

    // i-rotamer fully in registers (broadcast reads, 6x ds_read_b128).
    float4 xi4[6];
    {
        const float4* rowI = (const float4*)&ldsI[ty * CSTR];
#pragma unroll
        for (int k = 0; k < 6; ++k) xi4[k] = rowI[k];
    }
    float* xi = (float*)xi4;

    // Per-atom squared norms; pre-scale xi by -2 so d2 = (sqi+sqj) + sum(xi2*xj).
    float sqi[NATOM];
#pragma unroll
    for (int a = 0; a < NATOM; ++a)
        sqi[a] = fmaf(xi[a*3+2], xi[a*3+2], fmaf(xi[a*3+1], xi[a*3+1], xi[a*3+0]*xi[a*3+0]));
#pragma unroll
    for (int k = 0; k < 24; ++k) xi[k] = xi[k] * -2.0f;

    const float SCH_S = -12102203.0f;   // -(2^23)/ln2  (Schraudolph exp)
    const float SCH_B = 1064866805.0f;  // bias
    const v2f veps = { EPS, EPS };
    const float* rowJ = &ldsJ[tx * CSTR];   // 16B-aligned row base

    v2f s0v = { 0.0f, 0.0f }, s1v = { 0.0f, 0.0f };

#pragma unroll
    for (int bp = 0; bp < 4; ++bp) {
        // Stream 6 j-floats for atoms (2bp, 2bp+1); static offsets -> merged ds_reads.
        const float j0 = rowJ[bp*6 + 0];
        const float j1 = rowJ[bp*6 + 1];
        const float j2 = rowJ[bp*6 + 2];
        const float j3 = rowJ[bp*6 + 3];
        const float j4 = rowJ[bp*6 + 4];
        const float j5 = rowJ[bp*6 + 5];
        const v2f ax = { j0, j3 };
        const v2f ay = { j1, j4 };
        const v2f az = { j2, j5 };
        const v2f sj = __builtin_elementwise_fma(az, az,
                        __builtin_elementwise_fma(ay, ay, ax * ax));
#pragma unroll
        for (int a = 0; a < NATOM; ++a) {
            v2f t = sj + sqi[a];                                    // pk_add (splat)
            t = __builtin_elementwise_fma((v2f)(xi[a*3+0]), ax, t);
            t = __builtin_elementwise_fma((v2f)(xi[a*3+1]), ay, t);
            t = __builtin_elementwise_fma((v2f)(xi[a*3+2]), az, t); // t = d2 pair
            t = __builtin_elementwise_max(t, veps);
            const v2f rs = { __builtin_amdgcn_rsqf(t.x),
                             __builtin_amdgcn_rsqf(t.y) };
            s0v = __builtin_elementwise_fma(rs, rs, s0v);           // += 1/d2
            const v2f dv = t * rs;                                  // sqrt(d2)
            const v2f st = __builtin_elementwise_fma(dv, (v2f)(SCH_S), (v2f)(SCH_B));
            v2f e;
            e.x = __int_as_float((int)st.x);                        // ~ exp(-d)
            e.y = __int_as_float((int)st.y);
            s1v += e;
        }
    }
    const float s0 = s0v.x + s0v.y;
    const float s1 = s1v.x + s1v.y;

    // Stage results for the coalesced mirror write.
    res0[ty * SSTR + tx] = s0;
    res1[ty * SSTR + tx] = s1;

    const int nnz = NPOSE * NROT * NROT;
    const int gi  = ti * TS + ty;
    const int gj  = tj * TS + tx;
    const int n   = (p * NROT + gi) * NROT + gj;

    out[0 * nnz + n] = s0;
    out[1 * nnz + n] = s1;
    out[2 * nnz + n] = (float)p;
    out[3 * nnz + n] = (float)(p * NROT + gi);
    out[4 * nnz + n] = (float)(p * NROT + gj);

    if (ti != tj) {              // block-uniform branch
        __syncthreads();
        const float m0 = res0[tx * SSTR + ty];   // value of pair (ti*TS+tx, tj*TS+ty)
        const float m1 = res1[tx * SSTR + ty];
        const int mi = tj * TS + ty;
        const int mj = ti * TS + tx;
        const int nm = (p * NROT + mi) * NROT + mj;
        out[0 * nnz + nm] = m0;
        out[1 * nnz + nm] = m1;
        out[2 * nnz + nm] = (float)p;
        out[3 * nnz + nm] = (float)(p * NROT + mi);
        out[4 * nnz + nm] = (float)(p * NROT + mj);
    }
}

extern "C" void kernel_launch(void* const* d_in, const int* in_sizes, int n_in,
                              void* d_out, int out_size, void* d_ws, size_t ws_size,
                              hipStream_t stream) {
    (void)in_sizes; (void)n_in; (void)d_ws; (void)ws_size; (void)out_size;
    const float* coords = (const float*)d_in[0];
    float* out = (float*)d_out;

    dim3 grid(NPOSE * NPAIR);   // 64 poses x 36 upper-triangle tile pairs = 2304 blocks
    dim3 block(256);
    rot_score_kernel<<<grid, block, 0, stream>>>(coords, out);
}

// Round 10
// 20.610 us; speedup vs baseline: 3.2759x; 3.2759x over previous
//
#include <hip/hip_runtime.h>

typedef float v2f __attribute__((ext_vector_type(2)));

// Structural constants (mirror reference)
#define NPOSE 64
#define NROT  128
#define NATOM 8
#define EPS   1e-2f

#define TS    16                 // rotamer tile size
#define NTILE (NROT / TS)        // 8 tiles per axis
#define NPAIR (NTILE * (NTILE + 1) / 2)   // 36 tile pairs (ti <= tj)
#define CSTR  28                 // coord LDS row stride: 24 + 4 pad -> 112B, 16B-aligned rows
#define SSTR  17                 // result tile row stride (16 + 1 pad)

// 128 threads/block: 16 i-rows x 8 j-column-pairs. v2f lanes = the two j rotamers.
__global__ __launch_bounds__(128, 4) void rot_score_kernel(
    const float* __restrict__ coords,
    float* __restrict__ out)
{
    __shared__ float ldsI[TS * CSTR];
    __shared__ float ldsJ[TS * CSTR];
    __shared__ float res0[TS * SSTR];
    __shared__ float res1[TS * SSTR];

    const int bid = blockIdx.x;
    const int p   = bid / NPAIR;
    int t = bid - p * NPAIR;
    int ti = 0;
    while (t >= NTILE - ti) { t -= NTILE - ti; ++ti; }   // unrank upper triangle
    const int tj = ti + t;

    const int tid = threadIdx.x;
    const float* src = coords + (size_t)p * (NROT * NATOM * 3);

    // Stage the two 16-rotamer coordinate sets (16 x 24 floats each), coalesced reads.
    for (int idx = tid; idx < 2 * TS * 24; idx += 128) {
        const int set = idx >= TS * 24;
        const int loc = idx - set * (TS * 24);
        const int r   = loc / 24;
        const int k   = loc - r * 24;
        const float v = src[(set ? tj : ti) * (TS * 24) + loc];
        (set ? ldsJ : ldsI)[r * CSTR + k] = v;
    }
    __syncthreads();

    const int ty  = tid >> 3;   // i within tile (0..15)
    const int txp = tid & 7;    // j column pair: cols 2*txp, 2*txp+1

    // i-rotamer fully in registers (broadcast reads, 6x ds_read_b128).
    float4 xi4[6];
    {
        const float4* rowI = (const float4*)&ldsI[ty * CSTR];
#pragma unroll
        for (int k = 0; k < 6; ++k) xi4[k] = rowI[k];
    }
    float* xi = (float*)xi4;

    // Per-atom squared norms; pre-scale xi by -2 so d2 = (sqi+sqj) + sum(xi2*xj).
    float sqi[NATOM];
#pragma unroll
    for (int a = 0; a < NATOM; ++a)
        sqi[a] = fmaf(xi[a*3+2], xi[a*3+2], fmaf(xi[a*3+1], xi[a*3+1], xi[a*3+0]*xi[a*3+0]));
#pragma unroll
    for (int k = 0; k < 24; ++k) xi[k] = xi[k] * -2.0f;

    const float SCH_S = -12102203.0f;   // -(2^23)/ln2  (Schraudolph exp)
    const float SCH_B = 1064866805.0f;  // bias
    const v2f veps = { EPS, EPS };
    const float* rowJA = &ldsJ[(txp * 2 + 0) * CSTR];
    const float* rowJB = &ldsJ[(txp * 2 + 1) * CSTR];

    // Accumulators: .x = column A (2*txp), .y = column B (2*txp+1).
    v2f s0v = { 0.0f, 0.0f }, s1v = { 0.0f, 0.0f };

#pragma unroll
    for (int bp = 0; bp < 4; ++bp) {
        // Atoms 2bp (even) and 2bp+1 (odd) for both j rotamers.
        const float A0 = rowJA[bp*6 + 0], A1 = rowJA[bp*6 + 1], A2 = rowJA[bp*6 + 2];
        const float A3 = rowJA[bp*6 + 3], A4 = rowJA[bp*6 + 4], A5 = rowJA[bp*6 + 5];
        const float B0 = rowJB[bp*6 + 0], B1 = rowJB[bp*6 + 1], B2 = rowJB[bp*6 + 2];
        const float B3 = rowJB[bp*6 + 3], B4 = rowJB[bp*6 + 4], B5 = rowJB[bp*6 + 5];
        const v2f ex = { A0, B0 }, ey = { A1, B1 }, ez = { A2, B2 };   // even atom
        const v2f ox = { A3, B3 }, oy = { A4, B4 }, oz = { A5, B5 };   // odd atom
        const v2f sje = __builtin_elementwise_fma(ez, ez,
                         __builtin_elementwise_fma(ey, ey, ex * ex));
        const v2f sjo = __builtin_elementwise_fma(oz, oz,
                         __builtin_elementwise_fma(oy, oy, ox * ox));
#pragma unroll
        for (int a = 0; a < NATOM; ++a) {
            // even b-atom vs i-atom a (two j rotamers at once)
            v2f te = sje + sqi[a];
            te = __builtin_elementwise_fma((v2f)(xi[a*3+0]), ex, te);
            te = __builtin_elementwise_fma((v2f)(xi[a*3+1]), ey, te);
            te = __builtin_elementwise_fma((v2f)(xi[a*3+2]), ez, te);
            te = __builtin_elementwise_max(te, veps);
            const v2f rse = { __builtin_amdgcn_rsqf(te.x), __builtin_amdgcn_rsqf(te.y) };
            s0v = __builtin_elementwise_fma(rse, rse, s0v);
            const v2f dve = te * rse;
            const v2f ste = __builtin_elementwise_fma(dve, (v2f)(SCH_S), (v2f)(SCH_B));
            v2f ee; ee.x = __int_as_float((int)ste.x); ee.y = __int_as_float((int)ste.y);
            s1v += ee;

            // odd b-atom vs i-atom a (independent chain -> ILP)
            v2f to = sjo + sqi[a];
            to = __builtin_elementwise_fma((v2f)(xi[a*3+0]), ox, to);
            to = __builtin_elementwise_fma((v2f)(xi[a*3+1]), oy, to);
            to = __builtin_elementwise_fma((v2f)(xi[a*3+2]), oz, to);
            to = __builtin_elementwise_max(to, veps);
            const v2f rso = { __builtin_amdgcn_rsqf(to.x), __builtin_amdgcn_rsqf(to.y) };
            s0v = __builtin_elementwise_fma(rso, rso, s0v);
            const v2f dvo = to * rso;
            const v2f sto = __builtin_elementwise_fma(dvo, (v2f)(SCH_S), (v2f)(SCH_B));
            v2f eo; eo.x = __int_as_float((int)sto.x); eo.y = __int_as_float((int)sto.y);
            s1v += eo;
        }
    }

    // Stage results for the transposed mirror read.
    res0[ty * SSTR + txp * 2 + 0] = s0v.x;
    res0[ty * SSTR + txp * 2 + 1] = s0v.y;
    res1[ty * SSTR + txp * 2 + 0] = s1v.x;
    res1[ty * SSTR + txp * 2 + 1] = s1v.y;

    const int nnz  = NPOSE * NROT * NROT;
    const int gi   = ti * TS + ty;
    const int col0 = tj * TS + txp * 2;
    const int n    = (p * NROT + gi) * NROT + col0;      // even -> 8B aligned

    const float fp  = (float)p;
    const float ri  = (float)(p * NROT + gi);
    const float rj0 = (float)(p * NROT + col0);

    *(float2*)(out + (size_t)0 * nnz + n) = make_float2(s0v.x, s0v.y);
    *(float2*)(out + (size_t)1 * nnz + n) = make_float2(s1v.x, s1v.y);
    *(float2*)(out + (size_t)2 * nnz + n) = make_float2(fp, fp);
    *(float2*)(out + (size_t)3 * nnz + n) = make_float2(ri, ri);
    *(float2*)(out + (size_t)4 * nnz + n) = make_float2(rj0, rj0 + 1.0f);

    if (ti != tj) {              // block-uniform mirror
        __syncthreads();
        const float m0a = res0[(txp * 2 + 0) * SSTR + ty];
        const float m0b = res0[(txp * 2 + 1) * SSTR + ty];
        const float m1a = res1[(txp * 2 + 0) * SSTR + ty];
        const float m1b = res1[(txp * 2 + 1) * SSTR + ty];
        const int mi    = tj * TS + ty;
        const int mcol0 = ti * TS + txp * 2;
        const int nm    = (p * NROT + mi) * NROT + mcol0;
        const float mri  = (float)(p * NROT + mi);
        const float mrj0 = (float)(p * NROT + mcol0);

        *(float2*)(out + (size_t)0 * nnz + nm) = make_float2(m0a, m0b);
        *(float2*)(out + (size_t)1 * nnz + nm) = make_float2(m1a, m1b);
        *(float2*)(out + (size_t)2 * nnz + nm) = make_float2(fp, fp);
        *(float2*)(out + (size_t)3 * nnz + nm) = make_float2(mri, mri);
        *(float2*)(out + (size_t)4 * nnz + nm) = make_float2(mrj0, mrj0 + 1.0f);
    }
}

extern "C" void kernel_launch(void* const* d_in, const int* in_sizes, int n_in,
                              void* d_out, int out_size, void* d_ws, size_t ws_size,
                              hipStream_t stream) {
    (void)in_sizes; (void)n_in; (void)d_ws; (void)ws_size; (void)out_size;
    const float* coords = (const float*)d_in[0];
    float* out = (float*)d_out;

    dim3 grid(NPOSE * NPAIR);   // 64 poses x 36 upper-triangle tile pairs = 2304 blocks
    dim3 block(128);
    rot_score_kernel<<<grid, block, 0, stream>>>(coords, out);
}